// Round 7
// baseline (124.041 us; speedup 1.0000x reference)
//
#include <hip/hip_runtime.h>
#include <stdint.h>

// MetricLoss: B=1024, M=32, F=256, K_GRP=4
// out[0] = (1/1536) * sum_{same-group pairs i<j, m} ||x_i,m - x_j,m||^2
// out[1] = (1/522240) * sum_{g_i<g_j, m} relu(1 - ||x_i,m - x_j,m||^2)
//
// SINGLE kernel, 256 blocks (1/CU, co-resident), software grid barrier.
// ws layout:
//   [0,        16 MiB)  : xb  bf16 [32][1024][256]
//   [16 MiB, +128 KiB)  : sq  f32  [32][1024]
//   [+1 KiB]            : homo_part  f32 [256]
//   [+1 KiB]            : heter_part f32 [256]
//   [+8 B]              : ctr[2]  u32 {barrier, done}   (memset to 0 in-launch)

typedef __attribute__((ext_vector_type(4))) float f32x4;
typedef __attribute__((ext_vector_type(8))) short bf16x8;

#define XB_OFF    0u
#define SQ_OFF    16777216u
#define HOMO_OFF  16908288u   // 256 floats
#define HETER_OFF 16909312u   // 256 floats
#define CTR_OFF   16910336u   // 2 u32

__device__ __forceinline__ unsigned short f2bf(float f) {
  union { float f; unsigned u; } v; v.f = f;
  return (unsigned short)((v.u + 0x7fffu + ((v.u >> 16) & 1u)) >> 16);
}

__global__ __launch_bounds__(256) void k_all(const float* __restrict__ x,
                                             unsigned short* __restrict__ xb,
                                             float* __restrict__ sq,
                                             float* __restrict__ homo_part,
                                             float* __restrict__ heter_part,
                                             unsigned* __restrict__ ctr,
                                             float* __restrict__ out) {
  const int b    = blockIdx.x;          // 256
  const int tid  = threadIdx.x;
  const int lane = tid & 63;
  const int wid  = tid >> 6;

  __shared__ float part[4];
  __shared__ int lastflag;

  // ================= phase 1: convert + homo (block b owns group g=b) ======
  float homo_loc = 0.f;
  {
    const int g = b;
    #pragma unroll
    for (int k8 = 0; k8 < 8; ++k8) {
      const int m = wid * 8 + k8;       // 4 waves x 8 = 32 m's
      const float* base = x + ((size_t)(g * 4) * 32 + m) * 256 + lane * 4;
      float4 v[4];
      float sqv[4];
      #pragma unroll
      for (int a = 0; a < 4; ++a) {
        v[a] = *(const float4*)(base + a * 8192);
        float s = v[a].x * v[a].x + v[a].y * v[a].y + v[a].z * v[a].z + v[a].w * v[a].w;
        #pragma unroll
        for (int off = 32; off; off >>= 1) s += __shfl_xor(s, off, 64);
        sqv[a] = s;
        const int i = g * 4 + a;
        if (lane == 0) sq[m * 1024 + i] = s;
        ushort4 o;
        o.x = f2bf(v[a].x); o.y = f2bf(v[a].y); o.z = f2bf(v[a].z); o.w = f2bf(v[a].w);
        *(ushort4*)(xb + ((size_t)(m * 1024 + i)) * 256 + lane * 4) = o;
      }
      const float sx = v[0].x + v[1].x + v[2].x + v[3].x;
      const float sy = v[0].y + v[1].y + v[2].y + v[3].y;
      const float sz = v[0].z + v[1].z + v[2].z + v[3].z;
      const float sw = v[0].w + v[1].w + v[2].w + v[3].w;
      float s = sx * sx + sy * sy + sz * sz + sw * sw;
      #pragma unroll
      for (int off = 32; off; off >>= 1) s += __shfl_xor(s, off, 64);
      homo_loc += 4.f * (sqv[0] + sqv[1] + sqv[2] + sqv[3]) - s;  // wave-uniform
    }
  }
  if (lane == 0) part[wid] = homo_loc;
  __syncthreads();
  if (tid == 0) homo_part[b] = part[0] + part[1] + part[2] + part[3];

  // ================= grid barrier (release xb/sq, then arrive-and-spin) ====
  __threadfence();
  __syncthreads();
  if (tid == 0) {
    __hip_atomic_fetch_add(&ctr[0], 1u, __ATOMIC_ACQ_REL, __HIP_MEMORY_SCOPE_AGENT);
    unsigned v;
    do {
      __builtin_amdgcn_s_sleep(8);
      v = __hip_atomic_load(&ctr[0], __ATOMIC_ACQUIRE, __HIP_MEMORY_SCOPE_AGENT);
    } while (v < 256u);
  }
  __syncthreads();
  __threadfence();

  // ================= phase 2: heter, pure-global MFMA operands =============
  // XCD x (= b&7) handles m in {x, x+8, x+16, x+24}: per-XCD working set
  // 4 x 512 KB = 2 MB -> L2-resident. 144 tiles per XCD over 32 slots (4-5 ea).
  const int xcd  = b & 7;
  const int slot = b >> 3;               // 0..31
  const int wr = wid >> 1, wc = wid & 1; // 2x2 waves, each 64x64 output
  const int fr = lane & 15;
  const int kg = lane >> 4;

  float local = 0.f;

  for (int ti = slot; ti < 144; ti += 32) {
    const int mi = ti / 36;
    const int m  = xcd + 8 * mi;
    int t = ti % 36, r = 0;              // triangle decode: (r,c), c>=r
    while (t >= 8 - r) { t -= 8 - r; ++r; }
    const int c = r + t;
    if (c == r && wr == 1 && wc == 0) continue;   // provably-zero diag wave

    const unsigned short* Ab = xb + ((size_t)m * 1024 + r * 128 + wr * 64 + fr) * 256 + kg * 8;
    const unsigned short* Bb = xb + ((size_t)m * 1024 + c * 128 + wc * 64 + fr) * 256 + kg * 8;

    bf16x8 av[2][4], bv[2][4];
    #pragma unroll
    for (int q = 0; q < 4; ++q) {
      av[0][q] = *(const bf16x8*)(Ab + q * 4096);
      bv[0][q] = *(const bf16x8*)(Bb + q * 4096);
    }
    f32x4 acc[4][4] = {};
    #pragma unroll
    for (int kk = 0; kk < 8; ++kk) {
      if (kk < 7) {
        #pragma unroll
        for (int q = 0; q < 4; ++q) {
          av[(kk + 1) & 1][q] = *(const bf16x8*)(Ab + q * 4096 + (kk + 1) * 32);
          bv[(kk + 1) & 1][q] = *(const bf16x8*)(Bb + q * 4096 + (kk + 1) * 32);
        }
      }
      #pragma unroll
      for (int ai = 0; ai < 4; ++ai)
        #pragma unroll
        for (int bj = 0; bj < 4; ++bj)
          acc[ai][bj] = __builtin_amdgcn_mfma_f32_16x16x32_bf16(av[kk & 1][ai],
                                                                bv[kk & 1][bj],
                                                                acc[ai][bj], 0, 0, 0);
    }

    // epilogue: relu(1 - (sq_i + sq_j - 2*dot)), strict group mask
    const int ibase = r * 128 + wr * 64;
    const int jbase = c * 128 + wc * 64;
    const float* sqm = sq + m * 1024;
    float sqi[4][4];
    #pragma unroll
    for (int ai = 0; ai < 4; ++ai)
      #pragma unroll
      for (int rg = 0; rg < 4; ++rg)
        sqi[ai][rg] = sqm[ibase + ai * 16 + kg * 4 + rg];
    #pragma unroll
    for (int bj = 0; bj < 4; ++bj) {
      const int j = jbase + bj * 16 + fr;           // C/D: col = lane&15
      const float sqj = sqm[j];
      const int gj = j >> 2;
      #pragma unroll
      for (int ai = 0; ai < 4; ++ai)
        #pragma unroll
        for (int rg = 0; rg < 4; ++rg) {
          const int i = ibase + ai * 16 + kg * 4 + rg;  // row = (lane>>4)*4+reg
          const float dd = sqi[ai][rg] + sqj - 2.f * acc[ai][bj][rg];
          const float v = 1.f - dd;
          if (v > 0.f && gj > (i >> 2)) local += v;
        }
    }
  }

  #pragma unroll
  for (int off = 32; off; off >>= 1) local += __shfl_xor(local, off, 64);
  __syncthreads();                       // part[] reuse
  if (lane == 0) part[wid] = local;
  __syncthreads();
  if (tid == 0) heter_part[b] = part[0] + part[1] + part[2] + part[3];

  // ================= phase 3: last block reduces and writes out ============
  __threadfence();
  __syncthreads();
  if (tid == 0) {
    const unsigned prev = __hip_atomic_fetch_add(&ctr[1], 1u, __ATOMIC_ACQ_REL,
                                                 __HIP_MEMORY_SCOPE_AGENT);
    lastflag = (prev == 255u);
  }
  __syncthreads();
  if (!lastflag) return;
  __threadfence();

  float h = homo_part[tid];
  #pragma unroll
  for (int off = 32; off; off >>= 1) h += __shfl_xor(h, off, 64);
  float e = heter_part[tid];
  #pragma unroll
  for (int off = 32; off; off >>= 1) e += __shfl_xor(e, off, 64);
  __syncthreads();
  if (lane == 0) part[wid] = h;
  __syncthreads();
  if (tid == 0) out[0] = (part[0] + part[1] + part[2] + part[3]) * (1.0f / 1536.0f);
  __syncthreads();
  if (lane == 0) part[wid] = e;
  __syncthreads();
  if (tid == 0) out[1] = (part[0] + part[1] + part[2] + part[3]) * (1.0f / 522240.0f);
}

extern "C" void kernel_launch(void* const* d_in, const int* in_sizes, int n_in,
                              void* d_out, int out_size, void* d_ws, size_t ws_size,
                              hipStream_t stream) {
  const float* x = (const float*)d_in[0];
  float* out = (float*)d_out;
  char* ws = (char*)d_ws;
  unsigned short* xb = (unsigned short*)(ws + XB_OFF);
  float* sq          = (float*)(ws + SQ_OFF);
  float* homo_part   = (float*)(ws + HOMO_OFF);
  float* heter_part  = (float*)(ws + HETER_OFF);
  unsigned* ctr      = (unsigned*)(ws + CTR_OFF);

  hipMemsetAsync(ctr, 0, 2 * sizeof(unsigned), stream);
  k_all<<<256, 256, 0, stream>>>(x, xb, sq, homo_part, heter_part, ctr, out);
}

// Round 8
// 67.605 us; speedup vs baseline: 1.8348x; 1.8348x over previous
//
#include <hip/hip_runtime.h>
#include <stdint.h>

// MetricLoss: B=1024, M=32, F=256, K_GRP=4
// out[0] = (1/1536) * sum_{same-group pairs i<j, m} ||x_i,m - x_j,m||^2
// out[1] = (1/522240) * sum_{g_i<g_j, m} relu(1 - ||x_i,m - x_j,m||^2)
//
// DIAGNOSTIC ROUND: k_heter runs its full workload twice (rep-indexed
// partials; k_final consumes rep 0) so its dispatch exceeds the ~40 us
// harness fills and shows up in the rocprof top-5 with full counters.
//
// ws layout:
//   [0,        16 MiB)   : xb  bf16 [32][1024][256]
//   [16 MiB,  +128 KiB)  : sq  f32  [32][1024]
//   [+32 KiB]            : homo_part  f32 [8192]
//   [+9 KiB]             : heter_part f32 [2304]  (2 reps x 1152)

typedef __attribute__((ext_vector_type(4))) float f32x4;
typedef __attribute__((ext_vector_type(8))) short bf16x8;

#define XB_OFF    0u
#define SQ_OFF    16777216u
#define HOMO_OFF  16908288u   // 8192 floats
#define HETER_OFF 16941056u   // 2304 floats

#define AS1 __attribute__((address_space(1)))
#define AS3 __attribute__((address_space(3)))

__device__ __forceinline__ void async16(const void* g, void* l) {
  __builtin_amdgcn_global_load_lds((const AS1 unsigned int*)(uintptr_t)g,
                                   (AS3 unsigned int*)(uintptr_t)l, 16, 0, 0);
}

__device__ __forceinline__ unsigned short f2bf(float f) {
  union { float f; unsigned u; } v; v.f = f;
  return (unsigned short)((v.u + 0x7fffu + ((v.u >> 16) & 1u)) >> 16);
}

// ---- Kernel 1 (fused convert + homo) — unchanged
__global__ __launch_bounds__(256) void k_fused(const float* __restrict__ x,
                                               unsigned short* __restrict__ xb,
                                               float* __restrict__ sq,
                                               float* __restrict__ homo_part) {
  const int task = blockIdx.x * 4 + (threadIdx.x >> 6);  // task = g*32 + m
  const int lane = threadIdx.x & 63;
  const int g = task >> 5;
  const int m = task & 31;

  const float* base = x + ((size_t)(g * 4) * 32 + m) * 256 + lane * 4;
  float4 v[4];
  float sqv[4];
  #pragma unroll
  for (int a = 0; a < 4; ++a) {
    v[a] = *(const float4*)(base + a * 8192);
    float s = v[a].x * v[a].x + v[a].y * v[a].y + v[a].z * v[a].z + v[a].w * v[a].w;
    #pragma unroll
    for (int off = 32; off; off >>= 1) s += __shfl_xor(s, off, 64);
    sqv[a] = s;
    const int i = g * 4 + a;
    if (lane == 0) sq[m * 1024 + i] = s;
    ushort4 o;
    o.x = f2bf(v[a].x); o.y = f2bf(v[a].y); o.z = f2bf(v[a].z); o.w = f2bf(v[a].w);
    *(ushort4*)(xb + ((size_t)(m * 1024 + i)) * 256 + lane * 4) = o;
  }
  const float sx = v[0].x + v[1].x + v[2].x + v[3].x;
  const float sy = v[0].y + v[1].y + v[2].y + v[3].y;
  const float sz = v[0].z + v[1].z + v[2].z + v[3].z;
  const float sw = v[0].w + v[1].w + v[2].w + v[3].w;
  float s = sx * sx + sy * sy + sz * sz + sw * sw;
  #pragma unroll
  for (int off = 32; off; off >>= 1) s += __shfl_xor(s, off, 64);
  if (lane == 0)
    homo_part[task] = 4.f * (sqv[0] + sqv[1] + sqv[2] + sqv[3]) - s;
}

// Stage one 32 KB K-half of a 128x256 bf16 panel into LDS (8 loads/thread).
__device__ __forceinline__ void stage_half(const unsigned short* __restrict__ X,
                                           unsigned short* lds, int h, int tid) {
  #pragma unroll
  for (int i = 0; i < 8; ++i) {
    const int chunk = i * 256 + tid;        // 2048 chunks of 16B
    const int rr = chunk >> 4;
    const int c  = chunk & 15;
    const int gc = c ^ (rr & 7);
    async16(X + (size_t)rr * 256 + h * 128 + gc * 8,
            (char*)lds + h * 32768 + chunk * 16);
  }
}

// ---- Kernel 2: heter loss (R4 structure: full-K LDS-resident 128x128 tile,
// all loads upfront, two counted vmcnt waits) + sq row in LDS + REP x2.
__global__ __launch_bounds__(256) void k_heter(const unsigned short* __restrict__ xb,
                                               const float* __restrict__ sq,
                                               float* __restrict__ heter_part) {
  const int d = blockIdx.x;                  // 1152 = 8 * 144
  const int w = (d & 7) * 144 + (d >> 3);    // XCD chunk map
  const int m = w / 36;
  int t0 = w - m * 36, r = 0;
  while (t0 >= 8 - r) { t0 -= 8 - r; ++r; }
  const int cb = r + t0;
  const bool diag = (cb == r);

  __shared__ __align__(16) unsigned short ldsA[32768];   // 64 KB, 2 K-halves
  __shared__ __align__(16) unsigned short ldsB[32768];   // 64 KB
  __shared__ __align__(16) float sql[1024];              // 4 KB sq row
  __shared__ float part[4];

  const int tid = threadIdx.x;
  const int lane = tid & 63;
  const int wid = tid >> 6;
  const int wr = wid >> 1, wc = wid & 1;     // 2x2 waves, each 64x64 output
  const int fr = lane & 15;
  const int kg = lane >> 4;

  const unsigned short* Xa = xb + ((size_t)m * 1024 + r  * 128) * 256;
  const unsigned short* Xb = xb + ((size_t)m * 1024 + cb * 128) * 256;
  const unsigned short* ldsBb = diag ? ldsA : ldsB;

  for (int rep = 0; rep < 2; ++rep) {
    __syncthreads();                         // protect LDS from prior rep

    // issue sq (1 load) then all panel staging upfront
    async16(sq + m * 1024 + tid * 4, (char*)sql + tid * 16);
    if (diag) {
      stage_half(Xa, ldsA, 0, tid);
      stage_half(Xa, ldsA, 1, tid);
      asm volatile("s_waitcnt vmcnt(8)" ::: "memory");   // sql + A-h0 done
    } else {
      stage_half(Xa, ldsA, 0, tid);
      stage_half(Xb, ldsB, 0, tid);
      stage_half(Xa, ldsA, 1, tid);
      stage_half(Xb, ldsB, 1, tid);
      asm volatile("s_waitcnt vmcnt(16)" ::: "memory");  // sql + A-h0 + B-h0
    }
    __builtin_amdgcn_s_barrier();
    asm volatile("" ::: "memory");

    f32x4 acc[4][4] = {};
    #pragma unroll
    for (int h = 0; h < 2; ++h) {
      if (h == 1) {
        asm volatile("s_waitcnt vmcnt(0)" ::: "memory");
        __builtin_amdgcn_s_barrier();
        asm volatile("" ::: "memory");
      }
      const unsigned short* lA = ldsA + h * 16384;
      const unsigned short* lB = ldsBb + h * 16384;
      #pragma unroll
      for (int kk = 0; kk < 4; ++kk) {
        bf16x8 af[4], bv[4];
        #pragma unroll
        for (int q = 0; q < 4; ++q) {
          const int ra = wr * 64 + q * 16 + fr;
          const int ca = ((kk << 2) + kg) ^ (ra & 7);
          af[q] = *(const bf16x8*)(lA + ra * 128 + ca * 8);
          const int rbw = wc * 64 + q * 16 + fr;
          const int cbx = ((kk << 2) + kg) ^ (rbw & 7);
          bv[q] = *(const bf16x8*)(lB + rbw * 128 + cbx * 8);
        }
        #pragma unroll
        for (int ai = 0; ai < 4; ++ai)
          #pragma unroll
          for (int bj = 0; bj < 4; ++bj)
            acc[ai][bj] = __builtin_amdgcn_mfma_f32_16x16x32_bf16(af[ai], bv[bj],
                                                                  acc[ai][bj], 0, 0, 0);
      }
    }

    // epilogue: relu(1 - (sq_i + sq_j - 2*dot)), strict group mask, reduce
    const int ibase = r  * 128 + wr * 64;
    const int jbase = cb * 128 + wc * 64;

    float sqi[4][4];
    #pragma unroll
    for (int ai = 0; ai < 4; ++ai)
      #pragma unroll
      for (int rg = 0; rg < 4; ++rg)
        sqi[ai][rg] = sql[r * 128 + wr * 64 + ai * 16 + kg * 4 + rg];

    float local = 0.f;
    #pragma unroll
    for (int bj = 0; bj < 4; ++bj) {
      const int j = jbase + bj * 16 + fr;
      const float sqj = sql[cb * 128 + wc * 64 + bj * 16 + fr];
      const int gj = j >> 2;
      #pragma unroll
      for (int ai = 0; ai < 4; ++ai)
        #pragma unroll
        for (int rg = 0; rg < 4; ++rg) {
          const int i = ibase + ai * 16 + kg * 4 + rg;
          const float dd = sqi[ai][rg] + sqj - 2.f * acc[ai][bj][rg];
          const float v = 1.f - dd;
          if (v > 0.f && gj > (i >> 2)) local += v;
        }
    }
    #pragma unroll
    for (int off = 32; off; off >>= 1) local += __shfl_xor(local, off, 64);
    if (lane == 0) part[wid] = local;
    __syncthreads();
    if (tid == 0)
      heter_part[rep * 1152 + m * 36 + (w - m * 36)] =
          part[0] + part[1] + part[2] + part[3];
  }
}

// ---- Kernel 3: final reduction of partials + scaling (single block)
__global__ __launch_bounds__(256) void k_final(const float* __restrict__ homo_part,
                                               const float* __restrict__ heter_part,
                                               float* __restrict__ out) {
  __shared__ float red[8];
  const int tid = threadIdx.x;
  const int lane = tid & 63;
  const int wid = tid >> 6;

  float h = 0.f;
  for (int i = tid; i < 8192; i += 256) h += homo_part[i];
  #pragma unroll
  for (int off = 32; off; off >>= 1) h += __shfl_xor(h, off, 64);
  if (lane == 0) red[wid] = h;

  float e = 0.f;
  for (int i = tid; i < 1152; i += 256) e += heter_part[i];  // rep 0 only
  #pragma unroll
  for (int off = 32; off; off >>= 1) e += __shfl_xor(e, off, 64);
  if (lane == 0) red[4 + wid] = e;

  __syncthreads();
  if (tid == 0) out[0] = (red[0] + red[1] + red[2] + red[3]) * (1.0f / 1536.0f);
  if (tid == 1) out[1] = (red[4] + red[5] + red[6] + red[7]) * (1.0f / 522240.0f);
}

extern "C" void kernel_launch(void* const* d_in, const int* in_sizes, int n_in,
                              void* d_out, int out_size, void* d_ws, size_t ws_size,
                              hipStream_t stream) {
  const float* x = (const float*)d_in[0];
  float* out = (float*)d_out;
  char* ws = (char*)d_ws;
  unsigned short* xb = (unsigned short*)(ws + XB_OFF);
  float* sq         = (float*)(ws + SQ_OFF);
  float* homo_part  = (float*)(ws + HOMO_OFF);
  float* heter_part = (float*)(ws + HETER_OFF);

  k_fused<<<2048, 256, 0, stream>>>(x, xb, sq, homo_part);
  k_heter<<<1152, 256, 0, stream>>>(xb, sq, heter_part);
  k_final<<<1, 256, 0, stream>>>(homo_part, heter_part, out);
}